// Round 5
// baseline (139.735 us; speedup 1.0000x reference)
//
#include <hip/hip_runtime.h>
#include <stdint.h>

#define NPTS 2048

// ---- workspace layout (bytes) ----
// Bp fragment-ordered: [z][qb=16][s=64][frag 1KB]; frag = 16 q-cols x 32 k.
// Within a frag, lane-slot L*16 holds q-col n=L>>2, k-range (L&3)*8..+8 (bf16 pairs).
// Read side (k2): lane (quad=lane>>4, n=lane&15) reads offset n*64 + quad*16.
#define BP_OFF    0ULL
#define BP_BYTES  (8ULL * 16 * 64 * 1024)      // 8 MB
#define W2F_OFF   (BP_OFF + BP_BYTES)
#define W2F_BYTES (24ULL * 1024)               // 24 frags (kb0..5 x cb0..3)
#define WXF_OFF   (W2F_OFF + W2F_BYTES)
#define WXF_BYTES (24ULL * 1024)               // 24 frags (kb0..1 x cb0..11)

typedef __attribute__((ext_vector_type(8))) short bf16x8;
typedef __attribute__((ext_vector_type(4))) float f32x4;
typedef __attribute__((ext_vector_type(4))) unsigned int u32x4;

__device__ __forceinline__ unsigned f2bf(float f) {
  union { float f; unsigned u; } v; v.f = f;
  return (v.u + 0x7FFFu + ((v.u >> 16) & 1u)) >> 16;  // RNE
}

__device__ __forceinline__ bf16x8 pack8(const float4 a, const float4 b) {
  u32x4 r;
  r[0] = f2bf(a.x) | (f2bf(a.y) << 16);
  r[1] = f2bf(a.z) | (f2bf(a.w) << 16);
  r[2] = f2bf(b.x) | (f2bf(b.y) << 16);
  r[3] = f2bf(b.z) | (f2bf(b.w) << 16);
  union { u32x4 u; bf16x8 h; } c; c.u = r; return c.h;
}

// ================= K1: fragment-ordered Bp (coalesced 1KB stores) + weight frags =========
__global__ __launch_bounds__(256) void k1_prep(const float* __restrict__ feat,
                                               const float* __restrict__ geom,
                                               const float* __restrict__ Wk,
                                               unsigned char* __restrict__ ws) {
  const int blk = blockIdx.x, t = threadIdx.x;
  if (blk < 512) {
    const int z = blk >> 6, s = blk & 63;       // 32 b-points per s-chunk
    __shared__ float FT[64][37];                // F^T[j][k], pad 37 -> 2-way banks (free)
    __shared__ float g[96];
    const float* fz = feat + ((size_t)z * NPTS + s * 32) * 64;
    {
      const int row = t >> 3, j0 = (t & 7) << 3;
      const float4 v0 = *(const float4*)&fz[row * 64 + j0];
      const float4 v1 = *(const float4*)&fz[row * 64 + j0 + 4];
      FT[j0 + 0][row] = v0.x; FT[j0 + 1][row] = v0.y;
      FT[j0 + 2][row] = v0.z; FT[j0 + 3][row] = v0.w;
      FT[j0 + 4][row] = v1.x; FT[j0 + 5][row] = v1.y;
      FT[j0 + 6][row] = v1.z; FT[j0 + 7][row] = v1.w;
    }
    if (t < 96) g[t] = geom[((size_t)z * NPTS + s * 32) * 3 + t];
    __syncthreads();

    // wave w, lane L: writes frag slot L*16 of frags qb = it*4 + w (it = x = 0..3).
    // Slot L -> q-col n = L>>2, k-range k0 = (L&3)*8. j = (qb*16+n)&63 = w*16 + n
    // (iteration-invariant!) -> read F once, emit all 4 x-variants.
    const int w = t >> 6, L = t & 63;
    const int n = L >> 2, k0 = (L & 3) * 8;
    const int j = w * 16 + n;
    float f[8];
#pragma unroll
    for (int i = 0; i < 8; ++i) f[i] = FT[j][k0 + i];
    float gx[3][8];
#pragma unroll
    for (int x = 0; x < 3; ++x)
#pragma unroll
      for (int i = 0; i < 8; ++i) gx[x][i] = g[(k0 + i) * 3 + x];

    unsigned char* base = ws + BP_OFF + (size_t)z * 1048576 + (size_t)w * 65536 +
                          (size_t)s * 1024 + L * 16;
#pragma unroll
    for (int it = 0; it < 4; ++it) {            // x = it; frag qb = it*4 + w
      u32x4 pv;
#pragma unroll
      for (int p = 0; p < 4; ++p) {
        float f0 = f[2 * p], f1 = f[2 * p + 1];
        if (it < 3) { f0 *= gx[it][2 * p]; f1 *= gx[it][2 * p + 1]; }
        pv[p] = f2bf(f0) | (f2bf(f1) << 16);
      }
      *(u32x4*)(base + (size_t)it * 4 * 65536) = pv;   // wave-contiguous 1KB store
    }
  } else if (blk == 512) {
    // W2F frag (kb,cb): lane (quad,n) holds W2[k=kb*32+quad*8+jj][i=cb*16+n]
    for (int e = t; e < 1536; e += 256) {
      const int frag = e >> 6, lp = e & 63, nn = lp >> 2, qd = lp & 3;
      const int kb = frag >> 2, cb = frag & 3;
      u32x4 pv;
#pragma unroll
      for (int p = 0; p < 4; ++p) {
        const int k0 = kb * 32 + qd * 8 + 2 * p;
        const float v0 = Wk[(k0 >> 6) * 4096 + (cb * 16 + nn) * 64 + (k0 & 63)];
        const float v1 = Wk[((k0 + 1) >> 6) * 4096 + (cb * 16 + nn) * 64 + ((k0 + 1) & 63)];
        pv[p] = f2bf(v0) | (f2bf(v1) << 16);
      }
      *(u32x4*)(ws + W2F_OFF + (size_t)frag * 1024 + lp * 16) = pv;
    }
  } else {
    // WXF frag (kb,cb): lane holds Wk[xi>>6][xi&63][k=kb*32+quad*8+jj], xi=cb*16+n
    for (int e = t; e < 1536; e += 256) {
      const int frag = e >> 6, lp = e & 63, nn = lp >> 2, qd = lp & 3;
      const int kb = frag / 12, cb = frag % 12, xi = cb * 16 + nn;
      u32x4 pv;
#pragma unroll
      for (int p = 0; p < 4; ++p) {
        const int k0 = kb * 32 + qd * 8 + 2 * p;
        const float v0 = Wk[(xi >> 6) * 4096 + (xi & 63) * 64 + k0];
        const float v1 = Wk[(xi >> 6) * 4096 + (xi & 63) * 64 + k0 + 1];
        pv[p] = f2bf(v0) | (f2bf(v1) << 16);
      }
      *(u32x4*)(ws + WXF_OFF + (size_t)frag * 1024 + lp * 16) = pv;
    }
  }
}

// ====== K2: bitmask precompute -> barrier-free mask-GEMM -> fused epilogue ======
// grid 256 = (z = bx&7 [XCD-local], 64-row a-tile = bx>>3). 512 threads = 8 waves.
// Wave w: rows 16*(w&3)..+16, q-cols 128*(w>>2)..+128 (qb frags 8*(w>>2)+cb, cb=0..7).
// One mask unpack feeds 8 MFMAs. Zero barriers in the K-loop.
__global__ __launch_bounds__(512, 2) void k2_fused(const float* __restrict__ geom,
                                                   const unsigned char* __restrict__ ws,
                                                   float* __restrict__ out) {
  __shared__ __align__(16) float glds[NPTS * 3];   // 24 KB
  __shared__ unsigned int Mw[64 * 64];             // 16 KB: Mw[s][row], bit k = mask(row, s*32+k)
  __shared__ __align__(16) float Ct[64 * 256];     // 64 KB (epilogue transpose)

  const int t = threadIdx.x, lane = t & 63, w = t >> 6;   // w = 0..7
  const int quad = lane >> 4, n = lane & 15;
  const int z = blockIdx.x & 7, a0 = ((blockIdx.x >> 3) & 31) * 64;

  const float* gz = geom + (size_t)z * NPTS * 3;
#pragma unroll
  for (int i = 0; i < 3; ++i) {
    const int idx = (i * 512 + t) * 4;
    *(float4*)&glds[idx] = *(const float4*)&gz[idx];
  }
  __syncthreads();

  // ---- mask bit precompute: thread (row mr = t&63, s-range sg = t>>6) ----
  {
    const int mr = t & 63, sg = t >> 6;
    const float pa0 = glds[(a0 + mr) * 3 + 0];
    const float pa1 = glds[(a0 + mr) * 3 + 1];
    const float pa2 = glds[(a0 + mr) * 3 + 2];
#pragma unroll
    for (int si = 0; si < 8; ++si) {
      const int s = sg * 8 + si;
      unsigned bits = 0;
#pragma unroll
      for (int k8 = 0; k8 < 4; ++k8) {         // 8 b-points per group
        float v[24];
#pragma unroll
        for (int i = 0; i < 6; ++i)
          *(float4*)&v[i * 4] = *(const float4*)&glds[s * 96 + k8 * 24 + i * 4];
#pragma unroll
        for (int p = 0; p < 8; ++p) {
          const float d0 = v[p * 3 + 0] - pa0;
          const float d1 = v[p * 3 + 1] - pa1;
          const float d2 = v[p * 3 + 2] - pa2;
          const float n2 = fmaf(d2, d2, fmaf(d1, d1, d0 * d0));
          bits |= (n2 < 1.0f ? 1u : 0u) << (k8 * 8 + p);
        }
      }
      Mw[s * 64 + mr] = bits;
    }
  }
  __syncthreads();  // Mw READ-ONLY from here; no more barriers until epilogue

  // ---- barrier-free K-loop ----
  const unsigned char* bpz = ws + BP_OFF + (size_t)z * 1048576;
  const int fragoff = n * 64 + quad * 16;
  const int qsh = quad * 8;
  const int rbase = 16 * (w & 3);
  const int qb0 = 8 * (w >> 2);

  f32x4 acc[8];
#pragma unroll
  for (int cb = 0; cb < 8; ++cb)
#pragma unroll
    for (int r = 0; r < 4; ++r) acc[cb][r] = 0.f;

  bf16x8 Bf0[8], Bf1[8];
#pragma unroll
  for (int cb = 0; cb < 8; ++cb) {
    Bf0[cb] = *(const bf16x8*)(bpz + (size_t)(qb0 + cb) * 65536 + 0 * 1024 + fragoff);
    Bf1[cb] = *(const bf16x8*)(bpz + (size_t)(qb0 + cb) * 65536 + 1 * 1024 + fragoff);
  }

#define STEP(SS, BB)                                                              \
  {                                                                               \
    const unsigned mq = Mw[(SS) * 64 + rbase + n] >> qsh;                         \
    u32x4 aw;                                                                     \
    aw[0] = (mq & 1u)   * 0x3F80u | (mq & 2u)   * 0x1FC00000u;                    \
    aw[1] = (mq & 4u)   * 0x0FE0u | (mq & 8u)   * 0x07F00000u;                    \
    aw[2] = (mq & 16u)  * 0x03F8u | (mq & 32u)  * 0x01FC0000u;                    \
    aw[3] = (mq & 64u)  * 0xFEu   | (mq & 128u) * 0x007F0000u;                    \
    union { u32x4 u; bf16x8 h; } cv; cv.u = aw;                                   \
    _Pragma("unroll") for (int cb = 0; cb < 8; ++cb)                              \
      acc[cb] = __builtin_amdgcn_mfma_f32_16x16x32_bf16(cv.h, BB[cb],             \
                                                        acc[cb], 0, 0, 0);        \
    const int sl = ((SS) + 2) > 63 ? 63 : ((SS) + 2);                             \
    _Pragma("unroll") for (int cb = 0; cb < 8; ++cb)                              \
      BB[cb] = *(const bf16x8*)(bpz + (size_t)(qb0 + cb) * 65536 +                \
                                (size_t)sl * 1024 + fragoff);                     \
  }

  for (int s2 = 0; s2 < 64; s2 += 2) {
    STEP(s2, Bf0)
    STEP(s2 + 1, Bf1)
  }
#undef STEP

  // ---- epilogue: acc -> Ct (XOR chunk swizzle, single pass) ----
#pragma unroll
  for (int cb = 0; cb < 8; ++cb)
#pragma unroll
    for (int r = 0; r < 4; ++r) {
      const int row = rbase + quad * 4 + r;            // C/D: row = quad*4+r
      const int col = (qb0 + cb) * 16 + n;             // C/D: col = n
      Ct[row * 256 + (((col >> 2) ^ row) << 2) + (col & 3)] = acc[cb][r];
    }
  __syncthreads();

  if (w < 4) {
    const int lm = 16 * w + n;                         // final-GEMM A row
    bf16x8 Across[8];
#pragma unroll
    for (int kb = 0; kb < 8; ++kb) {
      const int c0 = (kb * 8 + quad * 2) ^ lm;
      const int c1 = (kb * 8 + quad * 2 + 1) ^ lm;
      const float4 f0 = *(const float4*)&Ct[lm * 256 + c0 * 4];
      const float4 f1 = *(const float4*)&Ct[lm * 256 + c1 * 4];
      Across[kb] = pack8(f0, f1);
    }

    // out = C[:, :192] @ W2  -  sum_x g_a[x] * (T0 @ Wx); weight frags from L2
    f32x4 mn[4], V[12];
#pragma unroll
    for (int i = 0; i < 4; ++i)
#pragma unroll
      for (int r = 0; r < 4; ++r) mn[i][r] = 0.f;
#pragma unroll
    for (int i = 0; i < 12; ++i)
#pragma unroll
      for (int r = 0; r < 4; ++r) V[i][r] = 0.f;

    const unsigned char* w2f = ws + W2F_OFF;
    const unsigned char* wxf = ws + WXF_OFF;
#pragma unroll
    for (int kb = 0; kb < 6; ++kb)
#pragma unroll
      for (int cb = 0; cb < 4; ++cb) {
        const bf16x8 Bfr = *(const bf16x8*)(w2f + (size_t)(kb * 4 + cb) * 1024 + fragoff);
        mn[cb] = __builtin_amdgcn_mfma_f32_16x16x32_bf16(Across[kb], Bfr, mn[cb], 0, 0, 0);
      }
#pragma unroll
    for (int kb = 0; kb < 2; ++kb)
#pragma unroll
      for (int cb = 0; cb < 12; ++cb) {
        const bf16x8 Bfr = *(const bf16x8*)(wxf + (size_t)(kb * 12 + cb) * 1024 + fragoff);
        V[cb] = __builtin_amdgcn_mfma_f32_16x16x32_bf16(Across[6 + kb], Bfr, V[cb], 0, 0, 0);
      }

#pragma unroll
    for (int r = 0; r < 4; ++r) {
      const int af = a0 + 16 * w + quad * 4 + r;       // C/D row = quad*4 + r
      const float g0 = glds[af * 3 + 0], g1 = glds[af * 3 + 1], g2 = glds[af * 3 + 2];
#pragma unroll
      for (int cb = 0; cb < 4; ++cb) {
        const float v = mn[cb][r] - g0 * V[cb][r] - g1 * V[cb + 4][r] - g2 * V[cb + 8][r];
        out[((size_t)z * NPTS + af) * 64 + cb * 16 + n] = v;
      }
    }
  }
}

extern "C" void kernel_launch(void* const* d_in, const int* in_sizes, int n_in,
                              void* d_out, int out_size, void* d_ws, size_t ws_size,
                              hipStream_t stream) {
  const float* feat = (const float*)d_in[0];  // [8,2048,64]
  const float* geom = (const float*)d_in[1];  // [8,2048,3]
  const float* Wk   = (const float*)d_in[2];  // [3,64,64]
  float* out = (float*)d_out;                 // [8,2048,64] fp32
  unsigned char* ws = (unsigned char*)d_ws;   // ~8.44 MB used

  k1_prep<<<dim3(514), 256, 0, stream>>>(feat, geom, Wk, ws);
  k2_fused<<<dim3(256), 512, 0, stream>>>(geom, ws, out);
}

// Round 7
// 137.900 us; speedup vs baseline: 1.0133x; 1.0133x over previous
//
#include <hip/hip_runtime.h>
#include <stdint.h>

#define NPTS 2048

// ---- workspace layout (bytes) ----
// Bp fragment-ordered: [z][qb=16][s=64][frag 1KB]; frag slot L holds
// (q-col n=L>>2, k-range (L&3)*8..+8). Reader lane (quad,n) -> offset n*64+quad*16.
#define BP_OFF    0ULL
#define BP_BYTES  (8ULL * 16 * 64 * 1024)      // 8 MB
#define W2F_OFF   (BP_OFF + BP_BYTES)
#define W2F_BYTES (24ULL * 1024)               // 24 frags (kb0..5 x cb0..3)
#define WXF_OFF   (W2F_OFF + W2F_BYTES)
#define WXF_BYTES (24ULL * 1024)               // 24 frags (kb0..1 x cb0..11)

typedef __attribute__((ext_vector_type(8))) short bf16x8;
typedef __attribute__((ext_vector_type(4))) float f32x4;
typedef __attribute__((ext_vector_type(4))) unsigned int u32x4;

__device__ __forceinline__ unsigned f2bf(float f) {
  union { float f; unsigned u; } v; v.f = f;
  return (v.u + 0x7FFFu + ((v.u >> 16) & 1u)) >> 16;  // RNE
}

__device__ __forceinline__ bf16x8 pack8(const float4 a, const float4 b) {
  u32x4 r;
  r[0] = f2bf(a.x) | (f2bf(a.y) << 16);
  r[1] = f2bf(a.z) | (f2bf(a.w) << 16);
  r[2] = f2bf(b.x) | (f2bf(b.y) << 16);
  r[3] = f2bf(b.z) | (f2bf(b.w) << 16);
  union { u32x4 u; bf16x8 h; } c; c.u = r; return c.h;
}

// ================= K1: fragment-ordered Bp (coalesced 1KB stores) + weight frags =========
// VERBATIM from R4 (verified correct).
__global__ __launch_bounds__(256) void k1_prep(const float* __restrict__ feat,
                                               const float* __restrict__ geom,
                                               const float* __restrict__ Wk,
                                               unsigned char* __restrict__ ws) {
  const int blk = blockIdx.x, t = threadIdx.x;
  if (blk < 512) {
    const int z = blk >> 6, s = blk & 63;       // 32 b-points per s-chunk
    __shared__ float FT[64][37];                // F^T[j][k], pad 37 -> 2-way banks (free)
    __shared__ float g[96];
    const float* fz = feat + ((size_t)z * NPTS + s * 32) * 64;
    {
      const int row = t >> 3, j0 = (t & 7) << 3;
      const float4 v0 = *(const float4*)&fz[row * 64 + j0];
      const float4 v1 = *(const float4*)&fz[row * 64 + j0 + 4];
      FT[j0 + 0][row] = v0.x; FT[j0 + 1][row] = v0.y;
      FT[j0 + 2][row] = v0.z; FT[j0 + 3][row] = v0.w;
      FT[j0 + 4][row] = v1.x; FT[j0 + 5][row] = v1.y;
      FT[j0 + 6][row] = v1.z; FT[j0 + 7][row] = v1.w;
    }
    if (t < 96) g[t] = geom[((size_t)z * NPTS + s * 32) * 3 + t];
    __syncthreads();

    const int w = t >> 6, L = t & 63;
    const int n = L >> 2, k0 = (L & 3) * 8;
    const int j = w * 16 + n;
    float f[8];
#pragma unroll
    for (int i = 0; i < 8; ++i) f[i] = FT[j][k0 + i];
    float gx[3][8];
#pragma unroll
    for (int x = 0; x < 3; ++x)
#pragma unroll
      for (int i = 0; i < 8; ++i) gx[x][i] = g[(k0 + i) * 3 + x];

    unsigned char* base = ws + BP_OFF + (size_t)z * 1048576 + (size_t)w * 65536 +
                          (size_t)s * 1024 + L * 16;
#pragma unroll
    for (int it = 0; it < 4; ++it) {            // x = it; frag qb = it*4 + w
      u32x4 pv;
#pragma unroll
      for (int p = 0; p < 4; ++p) {
        float f0 = f[2 * p], f1 = f[2 * p + 1];
        if (it < 3) { f0 *= gx[it][2 * p]; f1 *= gx[it][2 * p + 1]; }
        pv[p] = f2bf(f0) | (f2bf(f1) << 16);
      }
      *(u32x4*)(base + (size_t)it * 4 * 65536) = pv;   // wave-contiguous 1KB store
    }
  } else if (blk == 512) {
    for (int e = t; e < 1536; e += 256) {
      const int frag = e >> 6, lp = e & 63, nn = lp >> 2, qd = lp & 3;
      const int kb = frag >> 2, cb = frag & 3;
      u32x4 pv;
#pragma unroll
      for (int p = 0; p < 4; ++p) {
        const int k0 = kb * 32 + qd * 8 + 2 * p;
        const float v0 = Wk[(k0 >> 6) * 4096 + (cb * 16 + nn) * 64 + (k0 & 63)];
        const float v1 = Wk[((k0 + 1) >> 6) * 4096 + (cb * 16 + nn) * 64 + ((k0 + 1) & 63)];
        pv[p] = f2bf(v0) | (f2bf(v1) << 16);
      }
      *(u32x4*)(ws + W2F_OFF + (size_t)frag * 1024 + lp * 16) = pv;
    }
  } else {
    for (int e = t; e < 1536; e += 256) {
      const int frag = e >> 6, lp = e & 63, nn = lp >> 2, qd = lp & 3;
      const int kb = frag / 12, cb = frag % 12, xi = cb * 16 + nn;
      u32x4 pv;
#pragma unroll
      for (int p = 0; p < 4; ++p) {
        const int k0 = kb * 32 + qd * 8 + 2 * p;
        const float v0 = Wk[(xi >> 6) * 4096 + (xi & 63) * 64 + k0];
        const float v1 = Wk[(xi >> 6) * 4096 + (xi & 63) * 64 + k0 + 1];
        pv[p] = f2bf(v0) | (f2bf(v1) << 16);
      }
      *(u32x4*)(ws + WXF_OFF + (size_t)frag * 1024 + lp * 16) = pv;
    }
  }
}

// ====== K2: bitmask precompute -> barrier-free mask-GEMM -> fused epilogue ======
// grid 256 = (z = bx&7 [XCD-local], a-tile = bx>>3). 1024 threads = 16 waves = 4/SIMD.
// Wave w: rows 16*(w&3)..+16, q-cols 64*(w>>2)..+64 (frags qb = 4*(w>>2)+cb, cb=0..3).
// One mask unpack feeds 4 MFMAs; B prefetched 4 steps deep; zero K-loop barriers.
__global__ __launch_bounds__(1024, 4) void k2_fused(const float* __restrict__ geom,
                                                    const unsigned char* __restrict__ ws,
                                                    float* __restrict__ out) {
  __shared__ __align__(16) float glds[NPTS * 3];   // 24 KB
  __shared__ unsigned int Mw[64 * 64];             // 16 KB: Mw[s][row], bit k = mask(row, s*32+k)
  __shared__ __align__(16) float Ct[64 * 256];     // 64 KB (epilogue transpose)

  const int t = threadIdx.x, lane = t & 63, w = t >> 6;   // w = 0..15
  const int quad = lane >> 4, n = lane & 15;
  const int z = blockIdx.x & 7, a0 = ((blockIdx.x >> 3) & 31) * 64;

  const float* gz = geom + (size_t)z * NPTS * 3;
#pragma unroll
  for (int i = 0; i < 2; ++i) {
    const int idx = i * 1024 + t;
    if (idx < 1536) ((float4*)glds)[idx] = ((const float4*)gz)[idx];
  }
  __syncthreads();

  // ---- mask bit precompute: thread (row mr = t&63, s-range sg = t>>6 in 0..15) ----
  {
    const int mr = t & 63, sg = t >> 6;
    const float pa0 = glds[(a0 + mr) * 3 + 0];
    const float pa1 = glds[(a0 + mr) * 3 + 1];
    const float pa2 = glds[(a0 + mr) * 3 + 2];
#pragma unroll
    for (int si = 0; si < 4; ++si) {
      const int s = sg * 4 + si;
      unsigned bits = 0;
#pragma unroll
      for (int k8 = 0; k8 < 4; ++k8) {         // 8 b-points per group
        float v[24];
#pragma unroll
        for (int i = 0; i < 6; ++i)
          *(float4*)&v[i * 4] = *(const float4*)&glds[s * 96 + k8 * 24 + i * 4];
#pragma unroll
        for (int p = 0; p < 8; ++p) {
          const float d0 = v[p * 3 + 0] - pa0;
          const float d1 = v[p * 3 + 1] - pa1;
          const float d2 = v[p * 3 + 2] - pa2;
          const float n2 = fmaf(d2, d2, fmaf(d1, d1, d0 * d0));
          bits |= (n2 < 1.0f ? 1u : 0u) << (k8 * 8 + p);
        }
      }
      Mw[s * 64 + mr] = bits;
    }
  }
  __syncthreads();  // Mw READ-ONLY from here; no barriers until after the K-loop

  // ---- barrier-free K-loop ----
  const unsigned char* bpz = ws + BP_OFF + (size_t)z * 1048576;
  const int fragoff = n * 64 + quad * 16;
  const int qsh = quad * 8;
  const int rbase = 16 * (w & 3);
  const int qb0 = 4 * (w >> 2);

  f32x4 acc[4];
#pragma unroll
  for (int cb = 0; cb < 4; ++cb)
#pragma unroll
    for (int r = 0; r < 4; ++r) acc[cb][r] = 0.f;

  bf16x8 Bf[4][4];                                  // [pipeline slot][cb], depth 4
#pragma unroll
  for (int jj = 0; jj < 4; ++jj)
#pragma unroll
    for (int cb = 0; cb < 4; ++cb)
      Bf[jj][cb] = *(const bf16x8*)(bpz + (size_t)(qb0 + cb) * 65536 +
                                    (size_t)jj * 1024 + fragoff);

#define BSTEP(SS, JJ)                                                          \
  {                                                                            \
    const unsigned mq = (Mw[(SS) * 64 + rbase + n] >> qsh) & 0xFFu;            \
    u32x4 aw;                                                                  \
    aw[0] = (mq & 1u)   * 0x3F80u | (mq & 2u)   * 0x1FC00000u;                 \
    aw[1] = (mq & 4u)   * 0x0FE0u | (mq & 8u)   * 0x07F00000u;                 \
    aw[2] = (mq & 16u)  * 0x03F8u | (mq & 32u)  * 0x01FC0000u;                 \
    aw[3] = (mq & 64u)  * 0xFEu   | (mq & 128u) * 0x007F0000u;                 \
    union { u32x4 u; bf16x8 h; } cv; cv.u = aw;                                \
    _Pragma("unroll") for (int cb = 0; cb < 4; ++cb)                           \
      acc[cb] = __builtin_amdgcn_mfma_f32_16x16x32_bf16(cv.h, Bf[JJ][cb],      \
                                                        acc[cb], 0, 0, 0);     \
    const int sp = (SS) + 4 > 63 ? 63 : (SS) + 4;                              \
    _Pragma("unroll") for (int cb = 0; cb < 4; ++cb)                           \
      Bf[JJ][cb] = *(const bf16x8*)(bpz + (size_t)(qb0 + cb) * 65536 +         \
                                    (size_t)sp * 1024 + fragoff);              \
  }

  for (int s4 = 0; s4 < 64; s4 += 4) {
    BSTEP(s4 + 0, 0) BSTEP(s4 + 1, 1) BSTEP(s4 + 2, 2) BSTEP(s4 + 3, 3)
  }
#undef BSTEP

  // ---- epilogue: acc -> Ct (XOR chunk swizzle, single pass, 16 waves) ----
#pragma unroll
  for (int cb = 0; cb < 4; ++cb)
#pragma unroll
    for (int r = 0; r < 4; ++r) {
      const int row = rbase + quad * 4 + r;            // C/D: row = quad*4+r
      const int col = (qb0 + cb) * 16 + n;             // C/D: col = n
      Ct[row * 256 + (((col >> 2) ^ row) << 2) + (col & 3)] = acc[cb][r];
    }
  __syncthreads();

  if (w < 4) {
    const int lm = 16 * w + n;                         // final-GEMM A row
    bf16x8 Across[8];
#pragma unroll
    for (int kb = 0; kb < 8; ++kb) {
      const int c0 = (kb * 8 + quad * 2) ^ lm;
      const int c1 = (kb * 8 + quad * 2 + 1) ^ lm;
      const float4 f0 = *(const float4*)&Ct[lm * 256 + c0 * 4];
      const float4 f1 = *(const float4*)&Ct[lm * 256 + c1 * 4];
      Across[kb] = pack8(f0, f1);
    }

    // out = C[:, :192] @ W2  -  sum_x g_a[x] * (T0 @ Wx); weight frags from L2
    f32x4 mn[4], V[12];
#pragma unroll
    for (int i = 0; i < 4; ++i)
#pragma unroll
      for (int r = 0; r < 4; ++r) mn[i][r] = 0.f;
#pragma unroll
    for (int i = 0; i < 12; ++i)
#pragma unroll
      for (int r = 0; r < 4; ++r) V[i][r] = 0.f;

    const unsigned char* w2f = ws + W2F_OFF;
    const unsigned char* wxf = ws + WXF_OFF;
#pragma unroll
    for (int kb = 0; kb < 6; ++kb)
#pragma unroll
      for (int cb = 0; cb < 4; ++cb) {
        const bf16x8 Bfr = *(const bf16x8*)(w2f + (size_t)(kb * 4 + cb) * 1024 + fragoff);
        mn[cb] = __builtin_amdgcn_mfma_f32_16x16x32_bf16(Across[kb], Bfr, mn[cb], 0, 0, 0);
      }
#pragma unroll
    for (int kb = 0; kb < 2; ++kb)
#pragma unroll
      for (int cb = 0; cb < 12; ++cb) {
        const bf16x8 Bfr = *(const bf16x8*)(wxf + (size_t)(kb * 12 + cb) * 1024 + fragoff);
        V[cb] = __builtin_amdgcn_mfma_f32_16x16x32_bf16(Across[6 + kb], Bfr, V[cb], 0, 0, 0);
      }

#pragma unroll
    for (int r = 0; r < 4; ++r) {
      const int af = a0 + 16 * w + quad * 4 + r;       // C/D row = quad*4 + r
      const float g0 = glds[af * 3 + 0], g1 = glds[af * 3 + 1], g2 = glds[af * 3 + 2];
#pragma unroll
      for (int cb = 0; cb < 4; ++cb) {
        const float v = mn[cb][r] - g0 * V[cb][r] - g1 * V[cb + 4][r] - g2 * V[cb + 8][r];
        out[((size_t)z * NPTS + af) * 64 + cb * 16 + n] = v;
      }
    }
  }
}

extern "C" void kernel_launch(void* const* d_in, const int* in_sizes, int n_in,
                              void* d_out, int out_size, void* d_ws, size_t ws_size,
                              hipStream_t stream) {
  const float* feat = (const float*)d_in[0];  // [8,2048,64]
  const float* geom = (const float*)d_in[1];  // [8,2048,3]
  const float* Wk   = (const float*)d_in[2];  // [3,64,64]
  float* out = (float*)d_out;                 // [8,2048,64] fp32
  unsigned char* ws = (unsigned char*)d_ws;   // ~8.44 MB used

  k1_prep<<<dim3(514), 256, 0, stream>>>(feat, geom, Wk, ws);
  k2_fused<<<dim3(256), 1024, 0, stream>>>(geom, ws, out);
}